// Round 1
// baseline (2752.421 us; speedup 1.0000x reference)
//
#include <hip/hip_runtime.h>
#include <math.h>

#define BB 4
#define TT 4096
#define CC 1024
#define HH 64

// ---------------------------------------------------------------------------
// Kernel 1: QKV projection. Grid = B*T/4 blocks, 64 threads (one per head dim).
// Each block computes q,k,v rows for 4 consecutive (b,t) rows.
// x loads are wave-uniform (broadcast), W loads are lane-coalesced.
// ---------------------------------------------------------------------------
__global__ __launch_bounds__(64) void qkv_kernel(
    const float* __restrict__ x,
    const float* __restrict__ Wq,
    const float* __restrict__ Wk,
    const float* __restrict__ Wv,
    float* __restrict__ Q,
    float* __restrict__ K,
    float* __restrict__ V)
{
    const int h    = threadIdx.x;            // 0..63
    const int row0 = blockIdx.x * 4;         // 4 rows per block

    float aq[4] = {0.f, 0.f, 0.f, 0.f};
    float ak[4] = {0.f, 0.f, 0.f, 0.f};
    float av[4] = {0.f, 0.f, 0.f, 0.f};

    for (int c = 0; c < CC; c += 4) {
        float wq[4], wk[4], wv[4];
#pragma unroll
        for (int j = 0; j < 4; ++j) {
            wq[j] = Wq[(c + j) * HH + h];
            wk[j] = Wk[(c + j) * HH + h];
            wv[j] = Wv[(c + j) * HH + h];
        }
#pragma unroll
        for (int r = 0; r < 4; ++r) {
            const float4 xv = *(const float4*)(&x[(size_t)(row0 + r) * CC + c]);
            aq[r] += xv.x * wq[0] + xv.y * wq[1] + xv.z * wq[2] + xv.w * wq[3];
            ak[r] += xv.x * wk[0] + xv.y * wk[1] + xv.z * wk[2] + xv.w * wk[3];
            av[r] += xv.x * wv[0] + xv.y * wv[1] + xv.z * wv[2] + xv.w * wv[3];
        }
    }

#pragma unroll
    for (int r = 0; r < 4; ++r) {
        const size_t o = (size_t)(row0 + r) * HH + h;
        Q[o] = aq[r];
        K[o] = ak[r];
        V[o] = av[r];
    }
}

// ---------------------------------------------------------------------------
// Kernel 2: causal attention with online softmax.
// One wave (64 lanes) per PAIR of query rows (t, T-1-t) so every wave does
// exactly T+1 row-updates (perfect balance) and shares K/V loads.
// Lane i holds head-dim i. Score = shfl_xor butterfly reduction.
// Grid = B*T/2 waves = 8192 waves = 2048 blocks of 256 threads.
// ---------------------------------------------------------------------------
__global__ __launch_bounds__(256) void attn_kernel(
    const float* __restrict__ Q,
    const float* __restrict__ K,
    const float* __restrict__ V,
    float* __restrict__ out)
{
    const int lane = threadIdx.x & 63;
    const int wave = threadIdx.x >> 6;
    const int w    = blockIdx.x * 4 + wave;   // global wave id in [0, B*T/2)
    const int b    = w >> 11;                 // / 2048
    const int tp   = w & 2047;
    const int ta   = tp;                      // short row:  s in [0, ta]
    const int tb   = TT - 1 - tp;             // long row:   s in [0, tb]

    const float scale = 1.0f / sqrtf((float)CC);  // NOTE: C**-0.5, not H**-0.5

    const float* Kb = K + (size_t)b * TT * HH;
    const float* Vb = V + (size_t)b * TT * HH;

    const float qa = Q[((size_t)b * TT + ta) * HH + lane] * scale;
    const float qb = Q[((size_t)b * TT + tb) * HH + lane] * scale;

    float ma = -INFINITY, la = 0.f, acca = 0.f;
    float mb = -INFINITY, lb = 0.f, accb = 0.f;

    for (int s = 0; s <= tb; ++s) {
        const float kv = Kb[(size_t)s * HH + lane];
        const float vv = Vb[(size_t)s * HH + lane];

        // ---- long row (always active) ----
        float pb = qb * kv;
#pragma unroll
        for (int off = 32; off >= 1; off >>= 1) pb += __shfl_xor(pb, off);
        {
            const float mn    = fmaxf(mb, pb);
            const float alpha = __expf(mb - mn);
            const float e     = __expf(pb - mn);
            lb   = lb * alpha + e;
            accb = accb * alpha + e * vv;
            mb   = mn;
        }

        // ---- short row (wave-uniform predicate) ----
        if (s <= ta) {
            float pa = qa * kv;
#pragma unroll
            for (int off = 32; off >= 1; off >>= 1) pa += __shfl_xor(pa, off);
            const float mn    = fmaxf(ma, pa);
            const float alpha = __expf(ma - mn);
            const float e     = __expf(pa - mn);
            la   = la * alpha + e;
            acca = acca * alpha + e * vv;
            ma   = mn;
        }
    }

    out[((size_t)b * TT + ta) * HH + lane] = acca / la;
    out[((size_t)b * TT + tb) * HH + lane] = accb / lb;
}

// ---------------------------------------------------------------------------
extern "C" void kernel_launch(void* const* d_in, const int* in_sizes, int n_in,
                              void* d_out, int out_size, void* d_ws, size_t ws_size,
                              hipStream_t stream)
{
    const float* x  = (const float*)d_in[0];
    const float* Wq = (const float*)d_in[1];
    const float* Wk = (const float*)d_in[2];
    const float* Wv = (const float*)d_in[3];

    float* Q = (float*)d_ws;                       // 4 MB
    float* K = Q + (size_t)BB * TT * HH;           // 4 MB
    float* V = K + (size_t)BB * TT * HH;           // 4 MB  (total 12 MB of ws)
    float* out = (float*)d_out;

    qkv_kernel<<<BB * TT / 4, 64, 0, stream>>>(x, Wq, Wk, Wv, Q, K, V);
    attn_kernel<<<BB * TT / 2 / 4, 256, 0, stream>>>(Q, K, V, out);
}

// Round 2
// 437.333 us; speedup vs baseline: 6.2937x; 6.2937x over previous
//
#include <hip/hip_runtime.h>
#include <hip/hip_bf16.h>
#include <math.h>

#define BB 4
#define TT 4096
#define CC 1024
#define HH 64

typedef __attribute__((ext_vector_type(8))) short short8;          // 8 bf16 = 4 VGPRs (MFMA A/B frag)
typedef __attribute__((ext_vector_type(8))) unsigned short ushort8;
typedef __attribute__((ext_vector_type(4))) float f32x4;           // MFMA C/D frag
typedef __attribute__((ext_vector_type(4))) unsigned int uint4v;   // 16B mover

// RNE float->bf16 (matches v_cvt semantics for finite values; inputs here are finite)
__device__ inline unsigned short f2bf(float f) {
    unsigned int u = __builtin_bit_cast(unsigned int, f);
    unsigned int r = u + 0x7fffu + ((u >> 16) & 1u);
    return (unsigned short)(r >> 16);
}

// ---------------------------------------------------------------------------
// Kernel 1: QKV projection -> bf16 Q (pre-scaled by C^-0.5 = 1/32), K, V.
// 4096 blocks x 64 threads; lane = head dim; 4 rows per block.
// ---------------------------------------------------------------------------
__global__ __launch_bounds__(64) void qkv_kernel(
    const float* __restrict__ x,
    const float* __restrict__ Wq,
    const float* __restrict__ Wk,
    const float* __restrict__ Wv,
    unsigned short* __restrict__ Qb,
    unsigned short* __restrict__ Kb,
    unsigned short* __restrict__ Vb)
{
    const int h    = threadIdx.x;
    const int row0 = blockIdx.x * 4;

    float aq[4] = {0.f, 0.f, 0.f, 0.f};
    float ak[4] = {0.f, 0.f, 0.f, 0.f};
    float av[4] = {0.f, 0.f, 0.f, 0.f};

    for (int c = 0; c < CC; c += 4) {
        float wq[4], wk[4], wv[4];
#pragma unroll
        for (int j = 0; j < 4; ++j) {
            wq[j] = Wq[(c + j) * HH + h];
            wk[j] = Wk[(c + j) * HH + h];
            wv[j] = Wv[(c + j) * HH + h];
        }
#pragma unroll
        for (int r = 0; r < 4; ++r) {
            const float4 xv = *(const float4*)(&x[(size_t)(row0 + r) * CC + c]);
            aq[r] += xv.x * wq[0] + xv.y * wq[1] + xv.z * wq[2] + xv.w * wq[3];
            ak[r] += xv.x * wk[0] + xv.y * wk[1] + xv.z * wk[2] + xv.w * wk[3];
            av[r] += xv.x * wv[0] + xv.y * wv[1] + xv.z * wv[2] + xv.w * wv[3];
        }
    }

#pragma unroll
    for (int r = 0; r < 4; ++r) {
        const int o = (row0 + r) * HH + h;
        Qb[o] = f2bf(aq[r] * 0.03125f);   // fold in scale = C^-0.5 = 1/32 (exact)
        Kb[o] = f2bf(ak[r]);
        Vb[o] = f2bf(av[r]);
    }
}

// ---------------------------------------------------------------------------
// Kernel 2: flash attention, bf16 MFMA 16x16x32.
// 256 blocks (B=4 x 64 q-tiles) x 256 threads (4 waves).
// Block owns 64 q-rows; wave owns 16. s-tiles of 64.
// Layouts (measured, m89/m120):
//   A-frag:  A[m=lane&15][k=quad*8+j]
//   B-frag:  B[k=quad*8+j][n=lane&15]
//   C/D:     row = quad*4+reg, col = lane&15
// LDS rows padded to 72 elems (144B, mult of 16B for b128; uniform bank load).
// ---------------------------------------------------------------------------
__global__ __launch_bounds__(256) void attn_kernel(
    const unsigned short* __restrict__ Qb,
    const unsigned short* __restrict__ Kb,
    const unsigned short* __restrict__ Vb,
    float* __restrict__ out)
{
    __shared__ unsigned short Ks[64][72];      // K-tile  [s][h]
    __shared__ unsigned short Vt[64][72];      // V-tile  [h][s] (transposed)
    __shared__ unsigned short Ps[4][16][72];   // per-wave P strip [t][s] bf16

    const int tid  = threadIdx.x;
    const int lane = tid & 63;
    const int wave = tid >> 6;
    const int n    = lane & 15;
    const int quad = lane >> 4;

    const int b     = blockIdx.x >> 6;
    const int qt    = blockIdx.x & 63;
    const int qbase = qt * 64;

    // Q A-frags: resident across the whole s-loop (Q already scaled by 1/32).
    const unsigned short* qptr = Qb + (b * TT + qbase + wave * 16 + n) * HH;
    const short8 aQ0 = *(const short8*)(qptr + quad * 8);
    const short8 aQ1 = *(const short8*)(qptr + 32 + quad * 8);

    f32x4 O[4];
#pragma unroll
    for (int ht = 0; ht < 4; ++ht) O[ht] = (f32x4){0.f, 0.f, 0.f, 0.f};
    float m_i[4] = {-INFINITY, -INFINITY, -INFINITY, -INFINITY};
    float l_i[4] = {0.f, 0.f, 0.f, 0.f};

    // staging assignments
    const int krow = tid >> 2;             // 0..63
    const int kch  = (tid & 3) * 16;       // 0,16,32,48
    const unsigned short* kbase = Kb + b * TT * HH;
    const int vs0 = (tid & 31) * 2;        // 0..62 even
    const int vh0 = (tid >> 5) * 8;        // 0..56
    const unsigned short* vbase = Vb + b * TT * HH;

    for (int st = 0; st <= qt; ++st) {
        const int sbase = st * 64;
        __syncthreads();   // protect LDS against previous iteration's readers

        // ---- stage K-tile [64s][64h] ----
        {
            const unsigned short* src = kbase + (sbase + krow) * HH + kch;
            *(uint4v*)&Ks[krow][kch]     = *(const uint4v*)(src);
            *(uint4v*)&Ks[krow][kch + 8] = *(const uint4v*)(src + 8);
        }
        // ---- stage V-tile transposed: Vt[h][s] = V[sbase+s][h] ----
        {
            const unsigned short* s0p = vbase + (sbase + vs0) * HH + vh0;
            const ushort8 ra = *(const ushort8*)(s0p);
            const ushort8 rb = *(const ushort8*)(s0p + HH);
#pragma unroll
            for (int j = 0; j < 8; ++j) {
                const unsigned int pk = (unsigned int)ra[j] | ((unsigned int)rb[j] << 16);
                *(unsigned int*)&Vt[vh0 + j][vs0] = pk;   // vs0 even -> dword aligned
            }
        }
        __syncthreads();

        // ---- S = Q K^T  (16 q-rows x 64 s-cols per wave) ----
        f32x4 S[4];
#pragma unroll
        for (int nt = 0; nt < 4; ++nt) {
            const short8 b0 = *(const short8*)&Ks[nt * 16 + n][quad * 8];
            const short8 b1 = *(const short8*)&Ks[nt * 16 + n][32 + quad * 8];
            f32x4 acc = (f32x4){0.f, 0.f, 0.f, 0.f};
            acc = __builtin_amdgcn_mfma_f32_16x16x32_bf16(aQ0, b0, acc, 0, 0, 0);
            acc = __builtin_amdgcn_mfma_f32_16x16x32_bf16(aQ1, b1, acc, 0, 0, 0);
            S[nt] = acc;
        }

        // ---- causal mask on the diagonal tile ----
        if (st == qt) {
            const int rbase = wave * 16 + quad * 4;   // local row of reg 0
#pragma unroll
            for (int nt = 0; nt < 4; ++nt) {
                const int col = nt * 16 + n;
#pragma unroll
                for (int r = 0; r < 4; ++r)
                    if (col > rbase + r) S[nt][r] = -INFINITY;
            }
        }

        // ---- online softmax (rows live across 16 lanes of a quad) ----
        float mt[4];
#pragma unroll
        for (int r = 0; r < 4; ++r)
            mt[r] = fmaxf(fmaxf(S[0][r], S[1][r]), fmaxf(S[2][r], S[3][r]));
#pragma unroll
        for (int off = 1; off <= 8; off <<= 1) {
#pragma unroll
            for (int r = 0; r < 4; ++r) mt[r] = fmaxf(mt[r], __shfl_xor(mt[r], off));
        }

        float alpha[4];
#pragma unroll
        for (int r = 0; r < 4; ++r) {
            const float mn = fmaxf(m_i[r], mt[r]);
            alpha[r] = __expf(m_i[r] - mn);   // 0 on first tile (-inf - finite)
            m_i[r] = mn;
        }

#pragma unroll
        for (int nt = 0; nt < 4; ++nt)
#pragma unroll
            for (int r = 0; r < 4; ++r)
                S[nt][r] = __expf(S[nt][r] - m_i[r]);   // masked -> exp(-inf)=0

        float rs[4];
#pragma unroll
        for (int r = 0; r < 4; ++r) rs[r] = (S[0][r] + S[1][r]) + (S[2][r] + S[3][r]);
#pragma unroll
        for (int off = 1; off <= 8; off <<= 1) {
#pragma unroll
            for (int r = 0; r < 4; ++r) rs[r] += __shfl_xor(rs[r], off);
        }

#pragma unroll
        for (int r = 0; r < 4; ++r) l_i[r] = l_i[r] * alpha[r] + rs[r];
#pragma unroll
        for (int ht = 0; ht < 4; ++ht)
#pragma unroll
            for (int r = 0; r < 4; ++r) O[ht][r] *= alpha[r];

        // ---- P: C-layout -> A-layout via per-wave LDS round-trip (bf16) ----
#pragma unroll
        for (int nt = 0; nt < 4; ++nt)
#pragma unroll
            for (int r = 0; r < 4; ++r)
                Ps[wave][quad * 4 + r][nt * 16 + n] = f2bf(S[nt][r]);
        asm volatile("s_waitcnt lgkmcnt(0)" ::: "memory");   // wave-private strip; no barrier needed
        const short8 aP0 = *(const short8*)&Ps[wave][n][quad * 8];
        const short8 aP1 = *(const short8*)&Ps[wave][n][32 + quad * 8];

        // ---- O += P V ----
#pragma unroll
        for (int ht = 0; ht < 4; ++ht) {
            const short8 bv0 = *(const short8*)&Vt[ht * 16 + n][quad * 8];
            const short8 bv1 = *(const short8*)&Vt[ht * 16 + n][32 + quad * 8];
            O[ht] = __builtin_amdgcn_mfma_f32_16x16x32_bf16(aP0, bv0, O[ht], 0, 0, 0);
            O[ht] = __builtin_amdgcn_mfma_f32_16x16x32_bf16(aP1, bv1, O[ht], 0, 0, 0);
        }
    }

    // ---- epilogue: O / l, fp32 out [b][t][h] ----
#pragma unroll
    for (int r = 0; r < 4; ++r) {
        const float inv = 1.0f / l_i[r];
        const int trow = qbase + wave * 16 + quad * 4 + r;
        float* op = out + (b * TT + trow) * HH;
#pragma unroll
        for (int ht = 0; ht < 4; ++ht)
            op[ht * 16 + n] = O[ht][r] * inv;
    }
}

// ---------------------------------------------------------------------------
extern "C" void kernel_launch(void* const* d_in, const int* in_sizes, int n_in,
                              void* d_out, int out_size, void* d_ws, size_t ws_size,
                              hipStream_t stream)
{
    const float* x  = (const float*)d_in[0];
    const float* Wq = (const float*)d_in[1];
    const float* Wk = (const float*)d_in[2];
    const float* Wv = (const float*)d_in[3];

    unsigned short* Qb = (unsigned short*)d_ws;            // 2 MB
    unsigned short* Kb = Qb + (size_t)BB * TT * HH;        // 2 MB
    unsigned short* Vb = Kb + (size_t)BB * TT * HH;        // 2 MB
    float* out = (float*)d_out;

    qkv_kernel<<<BB * TT / 4, 64, 0, stream>>>(x, Wq, Wk, Wv, Qb, Kb, Vb);
    attn_kernel<<<BB * 64, 256, 0, stream>>>(Qb, Kb, Vb, out);
}

// Round 3
// 230.775 us; speedup vs baseline: 11.9268x; 1.8951x over previous
//
#include <hip/hip_runtime.h>
#include <hip/hip_bf16.h>
#include <math.h>

#define BB 4
#define TT 4096
#define CC 1024
#define HH 64

typedef __attribute__((ext_vector_type(8))) short short8;          // 8 bf16 = 4 VGPRs (MFMA A/B frag)
typedef __attribute__((ext_vector_type(8))) unsigned short ushort8;
typedef __attribute__((ext_vector_type(4))) float f32x4;           // MFMA C/D frag
typedef __attribute__((ext_vector_type(4))) unsigned int uint4v;   // 16B mover

// RNE float->bf16
__device__ inline unsigned short f2bf(float f) {
    unsigned int u = __builtin_bit_cast(unsigned int, f);
    unsigned int r = u + 0x7fffu + ((u >> 16) & 1u);
    return (unsigned short)(r >> 16);
}

// ---------------------------------------------------------------------------
// Kernel 0: W transpose+convert. Wq|Wk|Wv [1024][64] fp32 -> Wt[192][1024] bf16.
// Wt[col][c] layout so B-frags (contiguous k) are 16B loads. Runs once, tiny.
// ---------------------------------------------------------------------------
__global__ __launch_bounds__(256) void wtrans_kernel(
    const float* __restrict__ Wq,
    const float* __restrict__ Wk,
    const float* __restrict__ Wv,
    unsigned short* __restrict__ Wt)
{
    const int idx = blockIdx.x * 256 + threadIdx.x;    // 0 .. 196607
    const int m   = idx >> 16;                         // matrix 0..2
    const int rem = idx & 0xFFFF;
    const int c   = rem >> 6;                          // 0..1023
    const int col = rem & 63;                          // 0..63
    const float* src = (m == 0) ? Wq : (m == 1) ? Wk : Wv;
    Wt[(m * 64 + col) * 1024 + c] = f2bf(src[c * 64 + col]);
}

// ---------------------------------------------------------------------------
// Kernel 1: QKV projection as bf16 MFMA GEMM [16384x1024]@[1024x192].
// 512 blocks x 256 threads. Block = 32 rows; wave = 48 cols (3 N-tiles).
// BK=64. A staged fp32->bf16 through LDS (coalesced); B-frags direct from
// L2-resident Wt. Q written pre-scaled by C^-0.5 = 1/32.
// ---------------------------------------------------------------------------
__global__ __launch_bounds__(256) void qkv_gemm(
    const float* __restrict__ x,
    const unsigned short* __restrict__ Wt,
    unsigned short* __restrict__ Qb,
    unsigned short* __restrict__ Kb,
    unsigned short* __restrict__ Vb)
{
    __shared__ unsigned short As[32][72];   // 32 rows x 64 k, pad to 72 (144B, 16B-mult)

    const int tid  = threadIdx.x;
    const int lane = tid & 63;
    const int wave = tid >> 6;
    const int n    = lane & 15;
    const int quad = lane >> 4;

    const int row0  = blockIdx.x * 32;
    const int ncol0 = wave * 48;

    // staging: thread loads 8 consecutive floats of one x row
    const int ar = tid >> 3;          // 0..31
    const int ac = (tid & 7) * 8;     // 0..56
    const float* xsrc = x + (size_t)(row0 + ar) * CC + ac;

    f32x4 acc[2][3];
#pragma unroll
    for (int mt = 0; mt < 2; ++mt)
#pragma unroll
        for (int nt = 0; nt < 3; ++nt) acc[mt][nt] = (f32x4){0.f, 0.f, 0.f, 0.f};

    for (int c = 0; c < CC; c += 64) {
        __syncthreads();   // protect As against previous iteration's readers
        {
            const float4 f0 = *(const float4*)(xsrc + c);
            const float4 f1 = *(const float4*)(xsrc + c + 4);
            ushort8 u;
            u[0] = f2bf(f0.x); u[1] = f2bf(f0.y); u[2] = f2bf(f0.z); u[3] = f2bf(f0.w);
            u[4] = f2bf(f1.x); u[5] = f2bf(f1.y); u[6] = f2bf(f1.z); u[7] = f2bf(f1.w);
            *(ushort8*)&As[ar][ac] = u;
        }
        __syncthreads();

        // B-frags from global Wt (L2-hot): B[k][n] = Wt[col][c + kt*32 + quad*8 + j]
        short8 bfrag[3][2];
#pragma unroll
        for (int nt = 0; nt < 3; ++nt) {
            const unsigned short* wp = Wt + (size_t)(ncol0 + nt * 16 + n) * 1024 + c + quad * 8;
            bfrag[nt][0] = *(const short8*)(wp);
            bfrag[nt][1] = *(const short8*)(wp + 32);
        }
        // A-frags from LDS
        short8 afrag[2][2];
#pragma unroll
        for (int mt = 0; mt < 2; ++mt) {
            afrag[mt][0] = *(const short8*)&As[mt * 16 + n][quad * 8];
            afrag[mt][1] = *(const short8*)&As[mt * 16 + n][32 + quad * 8];
        }
#pragma unroll
        for (int mt = 0; mt < 2; ++mt)
#pragma unroll
            for (int nt = 0; nt < 3; ++nt) {
                acc[mt][nt] = __builtin_amdgcn_mfma_f32_16x16x32_bf16(afrag[mt][0], bfrag[nt][0], acc[mt][nt], 0, 0, 0);
                acc[mt][nt] = __builtin_amdgcn_mfma_f32_16x16x32_bf16(afrag[mt][1], bfrag[nt][1], acc[mt][nt], 0, 0, 0);
            }
    }

    // epilogue: C/D layout row = quad*4+r, col = n (within 16x16 tile)
#pragma unroll
    for (int mt = 0; mt < 2; ++mt) {
#pragma unroll
        for (int nt = 0; nt < 3; ++nt) {
            const int colbase = ncol0 + nt * 16;            // wave-uniform, 16-aligned
            unsigned short* dst;
            float s;
            if (colbase < 64)       { dst = Qb; s = 0.03125f; }
            else if (colbase < 128) { dst = Kb - 64; s = 1.0f; }
            else                    { dst = Vb - 128; s = 1.0f; }
#pragma unroll
            for (int r = 0; r < 4; ++r) {
                const int row = row0 + mt * 16 + quad * 4 + r;
                dst[(size_t)row * HH + colbase + n] = f2bf(acc[mt][nt][r] * s);
            }
        }
    }
}

// ---------------------------------------------------------------------------
// Kernel 2: flash attention, bf16 MFMA 16x16x32 (unchanged from R2 — verified).
// ---------------------------------------------------------------------------
__global__ __launch_bounds__(256) void attn_kernel(
    const unsigned short* __restrict__ Qb,
    const unsigned short* __restrict__ Kb,
    const unsigned short* __restrict__ Vb,
    float* __restrict__ out)
{
    __shared__ unsigned short Ks[64][72];      // K-tile  [s][h]
    __shared__ unsigned short Vt[64][72];      // V-tile  [h][s] (transposed)
    __shared__ unsigned short Ps[4][16][72];   // per-wave P strip [t][s] bf16

    const int tid  = threadIdx.x;
    const int lane = tid & 63;
    const int wave = tid >> 6;
    const int n    = lane & 15;
    const int quad = lane >> 4;

    const int b     = blockIdx.x >> 6;
    const int qt    = blockIdx.x & 63;
    const int qbase = qt * 64;

    const unsigned short* qptr = Qb + (b * TT + qbase + wave * 16 + n) * HH;
    const short8 aQ0 = *(const short8*)(qptr + quad * 8);
    const short8 aQ1 = *(const short8*)(qptr + 32 + quad * 8);

    f32x4 O[4];
#pragma unroll
    for (int ht = 0; ht < 4; ++ht) O[ht] = (f32x4){0.f, 0.f, 0.f, 0.f};
    float m_i[4] = {-INFINITY, -INFINITY, -INFINITY, -INFINITY};
    float l_i[4] = {0.f, 0.f, 0.f, 0.f};

    const int krow = tid >> 2;
    const int kch  = (tid & 3) * 16;
    const unsigned short* kbase = Kb + b * TT * HH;
    const int vs0 = (tid & 31) * 2;
    const int vh0 = (tid >> 5) * 8;
    const unsigned short* vbase = Vb + b * TT * HH;

    for (int st = 0; st <= qt; ++st) {
        const int sbase = st * 64;
        __syncthreads();

        {
            const unsigned short* src = kbase + (sbase + krow) * HH + kch;
            *(uint4v*)&Ks[krow][kch]     = *(const uint4v*)(src);
            *(uint4v*)&Ks[krow][kch + 8] = *(const uint4v*)(src + 8);
        }
        {
            const unsigned short* s0p = vbase + (sbase + vs0) * HH + vh0;
            const ushort8 ra = *(const ushort8*)(s0p);
            const ushort8 rb = *(const ushort8*)(s0p + HH);
#pragma unroll
            for (int j = 0; j < 8; ++j) {
                const unsigned int pk = (unsigned int)ra[j] | ((unsigned int)rb[j] << 16);
                *(unsigned int*)&Vt[vh0 + j][vs0] = pk;
            }
        }
        __syncthreads();

        f32x4 S[4];
#pragma unroll
        for (int nt = 0; nt < 4; ++nt) {
            const short8 b0 = *(const short8*)&Ks[nt * 16 + n][quad * 8];
            const short8 b1 = *(const short8*)&Ks[nt * 16 + n][32 + quad * 8];
            f32x4 a = (f32x4){0.f, 0.f, 0.f, 0.f};
            a = __builtin_amdgcn_mfma_f32_16x16x32_bf16(aQ0, b0, a, 0, 0, 0);
            a = __builtin_amdgcn_mfma_f32_16x16x32_bf16(aQ1, b1, a, 0, 0, 0);
            S[nt] = a;
        }

        if (st == qt) {
            const int rbase = wave * 16 + quad * 4;
#pragma unroll
            for (int nt = 0; nt < 4; ++nt) {
                const int col = nt * 16 + n;
#pragma unroll
                for (int r = 0; r < 4; ++r)
                    if (col > rbase + r) S[nt][r] = -INFINITY;
            }
        }

        float mt[4];
#pragma unroll
        for (int r = 0; r < 4; ++r)
            mt[r] = fmaxf(fmaxf(S[0][r], S[1][r]), fmaxf(S[2][r], S[3][r]));
#pragma unroll
        for (int off = 1; off <= 8; off <<= 1) {
#pragma unroll
            for (int r = 0; r < 4; ++r) mt[r] = fmaxf(mt[r], __shfl_xor(mt[r], off));
        }

        float alpha[4];
#pragma unroll
        for (int r = 0; r < 4; ++r) {
            const float mn = fmaxf(m_i[r], mt[r]);
            alpha[r] = __expf(m_i[r] - mn);
            m_i[r] = mn;
        }

#pragma unroll
        for (int nt = 0; nt < 4; ++nt)
#pragma unroll
            for (int r = 0; r < 4; ++r)
                S[nt][r] = __expf(S[nt][r] - m_i[r]);

        float rs[4];
#pragma unroll
        for (int r = 0; r < 4; ++r) rs[r] = (S[0][r] + S[1][r]) + (S[2][r] + S[3][r]);
#pragma unroll
        for (int off = 1; off <= 8; off <<= 1) {
#pragma unroll
            for (int r = 0; r < 4; ++r) rs[r] += __shfl_xor(rs[r], off);
        }

#pragma unroll
        for (int r = 0; r < 4; ++r) l_i[r] = l_i[r] * alpha[r] + rs[r];
#pragma unroll
        for (int ht = 0; ht < 4; ++ht)
#pragma unroll
            for (int r = 0; r < 4; ++r) O[ht][r] *= alpha[r];

#pragma unroll
        for (int nt = 0; nt < 4; ++nt)
#pragma unroll
            for (int r = 0; r < 4; ++r)
                Ps[wave][quad * 4 + r][nt * 16 + n] = f2bf(S[nt][r]);
        asm volatile("s_waitcnt lgkmcnt(0)" ::: "memory");
        const short8 aP0 = *(const short8*)&Ps[wave][n][quad * 8];
        const short8 aP1 = *(const short8*)&Ps[wave][n][32 + quad * 8];

#pragma unroll
        for (int ht = 0; ht < 4; ++ht) {
            const short8 bv0 = *(const short8*)&Vt[ht * 16 + n][quad * 8];
            const short8 bv1 = *(const short8*)&Vt[ht * 16 + n][32 + quad * 8];
            O[ht] = __builtin_amdgcn_mfma_f32_16x16x32_bf16(aP0, bv0, O[ht], 0, 0, 0);
            O[ht] = __builtin_amdgcn_mfma_f32_16x16x32_bf16(aP1, bv1, O[ht], 0, 0, 0);
        }
    }

#pragma unroll
    for (int r = 0; r < 4; ++r) {
        const float inv = 1.0f / l_i[r];
        const int trow = qbase + wave * 16 + quad * 4 + r;
        float* op = out + (b * TT + trow) * HH;
#pragma unroll
        for (int ht = 0; ht < 4; ++ht)
            op[ht * 16 + n] = O[ht][r] * inv;
    }
}

// ---------------------------------------------------------------------------
extern "C" void kernel_launch(void* const* d_in, const int* in_sizes, int n_in,
                              void* d_out, int out_size, void* d_ws, size_t ws_size,
                              hipStream_t stream)
{
    const float* x  = (const float*)d_in[0];
    const float* Wq = (const float*)d_in[1];
    const float* Wk = (const float*)d_in[2];
    const float* Wv = (const float*)d_in[3];

    unsigned short* Qb = (unsigned short*)d_ws;            // 2 MB
    unsigned short* Kb = Qb + (size_t)BB * TT * HH;        // 2 MB
    unsigned short* Vb = Kb + (size_t)BB * TT * HH;        // 2 MB
    unsigned short* Wt = Vb + (size_t)BB * TT * HH;        // 384 KB
    float* out = (float*)d_out;

    wtrans_kernel<<<768, 256, 0, stream>>>(Wq, Wk, Wv, Wt);
    qkv_gemm<<<BB * TT / 32, 256, 0, stream>>>(x, Wt, Qb, Kb, Vb);
    attn_kernel<<<BB * 64, 256, 0, stream>>>(Qb, Kb, Vb, out);
}